// Round 13
// baseline (322.500 us; speedup 1.0000x reference)
//
#include <hip/hip_runtime.h>
#include <hip/hip_bf16.h>
#include <cstdint>

typedef __attribute__((ext_vector_type(4))) float f32x4;

#define DIM 256
#define TINV 10.0f
// TINV * log2(e): exp(S/T) == exp2(S * EXP2C)
#define EXP2C 14.426950408889634f
#define BM 128
#define BN 128
#define BK 64
#define GRID 1024     // 4 blocks/CU exactly co-resident (VGPR<=64, LDS 19.5KB)
#define TPB 512

// Device-scope arrive-and-spin grid barrier (CG grid.sync internals, no coop API).
// Release: __threadfence (L2 wb) before arrive; acquire: __threadfence (L2 inv)
// after spin. cnt[idx] zeroed by hipMemsetAsync before each launch.
__device__ __forceinline__ void grid_barrier(unsigned* cnt, int idx) {
    __syncthreads();
    if (threadIdx.x == 0) {
        __threadfence();
        atomicAdd(&cnt[idx], 1u);
        while (atomicAdd(&cnt[idx], 0u) < GRID) __builtin_amdgcn_s_sleep(8);
        __threadfence();
    }
    __syncthreads();
}

// ONE dispatch: normalize -> barrier -> gemm(2-3 tiles/block) -> barrier ->
// reduce -> arrive-only barrier -> final (block 0). GEMM body = R10/R11
// verified: fp8, 128x128 tile, 8 waves (2Mx4N), BK=64, XOR swizzle cc^(row&3),
// single-writer P scheme, no output atomics.
__launch_bounds__(TPB, 8)
__global__ void nt_fused(const float* __restrict__ y, uint8_t* __restrict__ ynq,
                         float* __restrict__ P, float* __restrict__ posterm,
                         float* __restrict__ blockpart, unsigned* __restrict__ cnt,
                         float* __restrict__ out, int N) {
    const int nt = N / BN;                      // 64
    const int T = nt * (nt + 1) / 2;            // 2080

    __shared__ __align__(16) uint8_t As[BM * BK];    // 8 KB
    __shared__ __align__(16) uint8_t Bs[BN * BK];    // 8 KB
    __shared__ float rowpart[4][BM];                 // 2 KB
    __shared__ float colpart[2][BN];                 // 1 KB
    __shared__ float redpart[8];

    int tid = threadIdx.x;
    int wave = tid >> 6, lane = tid & 63;
    int bid = blockIdx.x;

    // ---------------- Phase N: row-normalize y -> fp8 e4m3 (1 row/wave) -----
    {
        int row = bid * 8 + wave;               // 1024*8 = 8192 exactly
        float4 v = ((const float4*)(y + (size_t)row * DIM))[lane];
        float ss = v.x * v.x + v.y * v.y + v.z * v.z + v.w * v.w;
#pragma unroll
        for (int off = 1; off < 64; off <<= 1) ss += __shfl_xor(ss, off);
        float inv = 1.0f / fmaxf(sqrtf(ss), 1e-8f);
        int w = __builtin_amdgcn_cvt_pk_fp8_f32(v.x * inv, v.y * inv, 0, false);
        w = __builtin_amdgcn_cvt_pk_fp8_f32(v.z * inv, v.w * inv, w, true);
        ((int*)(ynq + (size_t)row * DIM))[lane] = w;
    }
    grid_barrier(cnt, 0);

    // ---------------- Phase G: sim-GEMM, 2-3 tiles per block ----------------
    int wr = wave >> 2, wc = wave & 3;               // 2 x 4 wave grid
    int l16 = lane & 15, lg = lane >> 4;
    int srow = tid >> 2, scc = tid & 3;
    int sgc = scc ^ (srow & 3);
    int swz[2];
#pragma unroll
    for (int kk = 0; kk < 2; ++kk)
        swz[kk] = (((kk * 2 + (lg >> 1)) ^ (l16 & 3)) * 16) + (lg & 1) * 8;
    int arow[4], brow[2];
#pragma unroll
    for (int m = 0; m < 4; ++m) arow[m] = (wr * 64 + m * 16 + l16) * BK;
#pragma unroll
    for (int n = 0; n < 2; ++n) brow[n] = (wc * 32 + n * 16 + l16) * BK;

    for (int orig = bid; orig < T; orig += GRID) {
        // bijective XCD-chunked swizzle (m204)
        int q = T >> 3, r = T & 7;
        int xcd = orig & 7, loc = orig >> 3;
        int t = (xcd < r ? xcd * (q + 1) : r * (q + 1) + (xcd - r) * q) + loc;
        // triangular index -> (by, bx), by <= bx (from bottom-right corner)
        int s = T - 1 - t;
        float ff = sqrtf(8.0f * (float)s + 1.0f);
        int j = (int)((ff - 1.0f) * 0.5f);
        while ((j + 1) * (j + 2) / 2 <= s) ++j;
        while (j * (j + 1) / 2 > s) --j;
        int k = s - j * (j + 1) / 2;
        int by = nt - 1 - j, bx = nt - 1 - k;
        int r0 = by * BM, c0 = bx * BN;

        f32x4 acc[4][2] = {};

        for (int k0 = 0; k0 < DIM; k0 += BK) {
            if (k0) __syncthreads();   // protect previous iter's LDS reads
            {
                const uint8_t* srcA = ynq + (size_t)(r0 + srow) * DIM + k0 + sgc * 16;
                __builtin_amdgcn_global_load_lds(
                    (const __attribute__((address_space(1))) uint32_t*)srcA,
                    (__attribute__((address_space(3))) uint32_t*)(As + wave * 1024), 16, 0, 0);
                const uint8_t* srcB = ynq + (size_t)(c0 + srow) * DIM + k0 + sgc * 16;
                __builtin_amdgcn_global_load_lds(
                    (const __attribute__((address_space(1))) uint32_t*)srcB,
                    (__attribute__((address_space(3))) uint32_t*)(Bs + wave * 1024), 16, 0, 0);
            }
            __syncthreads();   // drain; co-resident blocks hide the stall

#pragma unroll
            for (int kk = 0; kk < 2; ++kk) {
                long a[4], b[2];
#pragma unroll
                for (int m = 0; m < 4; ++m) a[m] = *(const long*)(As + arow[m] + swz[kk]);
#pragma unroll
                for (int n = 0; n < 2; ++n) b[n] = *(const long*)(Bs + brow[n] + swz[kk]);
#pragma unroll
                for (int m = 0; m < 4; ++m)
#pragma unroll
                    for (int n = 0; n < 2; ++n)
                        acc[m][n] = __builtin_amdgcn_mfma_f32_16x16x32_fp8_fp8(
                            a[m], b[n], acc[m][n], 0, 0, 0);
            }
        }

        // Epilogue. C/D layout (m89): col = lane&15, row = lg*4 + reg.
        bool diag = (by == bx);
        float colacc0 = 0.0f, colacc1 = 0.0f;
        float rp[16];
#pragma unroll
        for (int m = 0; m < 4; ++m) {
#pragma unroll
            for (int r2 = 0; r2 < 4; ++r2) {
                int grow = r0 + wr * 64 + m * 16 + lg * 4 + r2;
                float s0, s1;
                {
                    float S = acc[m][0][r2];
                    float e = __builtin_amdgcn_exp2f(S * EXP2C);
                    if (diag) {
                        int gcol = c0 + wc * 32 + l16;
                        if (gcol == grow) e = 0.0f;
                        if (gcol == (grow ^ 1)) posterm[grow] = -S * TINV;
                    }
                    s0 = e; colacc0 += e;
                }
                {
                    float S = acc[m][1][r2];
                    float e = __builtin_amdgcn_exp2f(S * EXP2C);
                    if (diag) {
                        int gcol = c0 + wc * 32 + 16 + l16;
                        if (gcol == grow) e = 0.0f;
                        if (gcol == (grow ^ 1)) posterm[grow] = -S * TINV;
                    }
                    s1 = e; colacc1 += e;
                }
                rp[m * 4 + r2] = s0 + s1;
            }
        }
        // Butterfly reduce-scatter over the 4 l16 bits (15 shfl); lane l16
        // ends holding the complete row-sum for rid = l16.
        int b0 = l16 & 1, b1 = (l16 >> 1) & 1, b2 = (l16 >> 2) & 1, b3 = (l16 >> 3) & 1;
        float t8[8];
#pragma unroll
        for (int i = 0; i < 8; ++i) {
            float send = b0 ? rp[2 * i] : rp[2 * i + 1];
            float keep = b0 ? rp[2 * i + 1] : rp[2 * i];
            t8[i] = keep + __shfl_xor(send, 1);
        }
        float t4[4];
#pragma unroll
        for (int i = 0; i < 4; ++i) {
            float send = b1 ? t8[2 * i] : t8[2 * i + 1];
            float keep = b1 ? t8[2 * i + 1] : t8[2 * i];
            t4[i] = keep + __shfl_xor(send, 2);
        }
        float t2[2];
#pragma unroll
        for (int i = 0; i < 2; ++i) {
            float send = b2 ? t4[2 * i] : t4[2 * i + 1];
            float keep = b2 ? t4[2 * i + 1] : t4[2 * i];
            t2[i] = keep + __shfl_xor(send, 4);
        }
        {
            float send = b3 ? t2[0] : t2[1];
            float keep = b3 ? t2[1] : t2[0];
            float rsum = keep + __shfl_xor(send, 8);
            int row_w = ((l16 >> 2) & 3) * 16 + lg * 4 + (l16 & 3);   // rid = l16
            rowpart[wc][wr * 64 + row_w] = rsum;
        }
        colacc0 += __shfl_xor(colacc0, 16); colacc0 += __shfl_xor(colacc0, 32);
        colacc1 += __shfl_xor(colacc1, 16); colacc1 += __shfl_xor(colacc1, 32);
        if (!diag && lane < 16) {
            colpart[wr][wc * 32 + lane] = colacc0;
            colpart[wr][wc * 32 + 16 + lane] = colacc1;
        }
        __syncthreads();
        // Single-writer stores: threads 0..127 row sums, 128..255 col sums.
        if (tid < BM) {
            P[(size_t)bx * N + r0 + tid] =
                rowpart[0][tid] + rowpart[1][tid] + rowpart[2][tid] + rowpart[3][tid];
        } else if (tid < 2 * BM && !diag) {
            int lcol = tid - BM;
            P[(size_t)by * N + c0 + lcol] = colpart[0][lcol] + colpart[1][lcol];
        }
    }
    grid_barrier(cnt, 1);

    // ---------------- Phase R: per-row log-sum (1 row/wave) ----------------
    {
        int row = bid * 8 + wave;
        float sacc = P[(size_t)lane * N + row];   // lane j reads slot j (64 slots)
#pragma unroll
        for (int off = 1; off < 64; off <<= 1) sacc += __shfl_xor(sacc, off);
        if (lane == 0) redpart[wave] = posterm[row] + logf(sacc);
        __syncthreads();
        if (tid == 0) {
            float bsum = 0.0f;
#pragma unroll
            for (int w2 = 0; w2 < 8; ++w2) bsum += redpart[w2];
            blockpart[bid] = bsum;
        }
    }

    // ---------------- Final barrier: arrive-only for blocks != 0 ----------
    __syncthreads();
    if (tid == 0) {
        __threadfence();
        atomicAdd(&cnt[2], 1u);
    }
    if (bid != 0) return;
    if (tid == 0) {
        while (atomicAdd(&cnt[2], 0u) < GRID) __builtin_amdgcn_s_sleep(8);
        __threadfence();
    }
    __syncthreads();

    // ---------------- Phase F: final scalar (block 0) ----------------------
    {
        float v = blockpart[tid] + blockpart[tid + TPB];
#pragma unroll
        for (int off = 1; off < 64; off <<= 1) v += __shfl_xor(v, off);
        if (lane == 0) redpart[wave] = v;
        __syncthreads();
        if (tid == 0) {
            float tot = 0.0f;
#pragma unroll
            for (int w2 = 0; w2 < 8; ++w2) tot += redpart[w2];
            out[0] = tot / (float)N;
        }
    }
}

extern "C" void kernel_launch(void* const* d_in, const int* in_sizes, int n_in,
                              void* d_out, int out_size, void* d_ws, size_t ws_size,
                              hipStream_t stream) {
    const float* y = (const float*)d_in[0];
    int N = in_sizes[0] / DIM;                 // 8192
    int nt = N / BN;                           // 64
    uint8_t* ynq = (uint8_t*)d_ws;             // N*DIM fp8 = 2 MB
    float* posterm = (float*)((char*)d_ws + (size_t)N * DIM);       // 32 KB
    float* P = posterm + N;                    // nt*N f32 = 2 MB
    float* blockpart = P + (size_t)nt * N;     // GRID f32
    unsigned* cnt = (unsigned*)(blockpart + GRID);   // 3 barrier counters
    float* out = (float*)d_out;

    hipMemsetAsync(cnt, 0, 3 * sizeof(unsigned), stream);   // zero barrier counters
    nt_fused<<<GRID, TPB, 0, stream>>>(y, ynq, P, posterm, blockpart, cnt, out, N);
}

// Round 14
// 36.378 us; speedup vs baseline: 8.8654x; 8.8654x over previous
//
#include <hip/hip_runtime.h>
#include <hip/hip_bf16.h>
#include <cstdint>

typedef __attribute__((ext_vector_type(4))) float f32x4;

#define DIM 256
#define TINV 10.0f
// TINV * log2(e): exp(S/T) == exp2(S * EXP2C)
#define EXP2C 14.426950408889634f
#define BM 128
#define BN 128
#define BK 64
#define NSLOT 64   // N/BN, compile-time for full unroll in reduce
#define NRED 128   // reduce blocks (N/64); power of two for ticket mask

// Kernel 1: row-normalize y (f32) -> fp8 e4m3 (OCP, RNE via cvt_pk).
__global__ void nt_normalize(const float* __restrict__ y, uint8_t* __restrict__ ynq,
                             int N) {
    int tid = threadIdx.x;
    int wave = tid >> 6, lane = tid & 63;
    int row = blockIdx.x * 4 + wave;
    float4 v = ((const float4*)(y + (size_t)row * DIM))[lane];
    float ss = v.x * v.x + v.y * v.y + v.z * v.z + v.w * v.w;
#pragma unroll
    for (int off = 1; off < 64; off <<= 1) ss += __shfl_xor(ss, off);
    float inv = 1.0f / fmaxf(sqrtf(ss), 1e-8f);
    int w = __builtin_amdgcn_cvt_pk_fp8_f32(v.x * inv, v.y * inv, 0, false);
    w = __builtin_amdgcn_cvt_pk_fp8_f32(v.z * inv, v.w * inv, w, true);
    ((int*)(ynq + (size_t)row * DIM))[lane] = w;
}

// Kernel 2: fp8 sim-GEMM + exp + partials + pos capture (R10 structure).
// 128x128 tile, 8 waves (2Mx4N, wave out 64x32), BK=64 K-loop, 32 waves/CU.
// Swizzle UPDATED: cc ^ ((row>>1)&3) -- bank audit: ds_read_b64 8B-granule
// index = 8(r&1) + 2(g^((r>>1)&3)) + h; over 16 lanes each granule hit
// exactly twice => 2-way conflict = free (m136). Old (row&3) was 4-way.
__launch_bounds__(512, 8)
__global__ void nt_gemm(const uint8_t* __restrict__ ynq, float* __restrict__ P,
                        float* __restrict__ posterm, int N) {
    const int nt = N / BN;                      // 64
    const int T = nt * (nt + 1) / 2;            // 2080
    // bijective XCD-chunked swizzle (m204)
    int orig = blockIdx.x;
    int q = T >> 3, r = T & 7;
    int xcd = orig & 7, loc = orig >> 3;
    int t = (xcd < r ? xcd * (q + 1) : r * (q + 1) + (xcd - r) * q) + loc;
    // triangular index -> (by, bx), by <= bx (count from bottom-right corner)
    int s = T - 1 - t;
    float f = sqrtf(8.0f * (float)s + 1.0f);
    int j = (int)((f - 1.0f) * 0.5f);
    while ((j + 1) * (j + 2) / 2 <= s) ++j;
    while (j * (j + 1) / 2 > s) --j;
    int k = s - j * (j + 1) / 2;
    int by = nt - 1 - j, bx = nt - 1 - k;

    __shared__ __align__(16) uint8_t As[BM * BK];    // 8 KB (fp8 K-tile)
    __shared__ __align__(16) uint8_t Bs[BN * BK];    // 8 KB
    __shared__ float rowpart[4][BM];                 // 2 KB [wc][row-in-tile]
    __shared__ float colpart[2][BN];                 // 1 KB [wr][col-in-tile]

    int r0 = by * BM, c0 = bx * BN;
    int tid = threadIdx.x;
    int wave = tid >> 6, lane = tid & 63;
    int wr = wave >> 2, wc = wave & 3;               // 2 x 4 wave grid
    int l16 = lane & 15, lg = lane >> 4;

    // Staging: LDS chunk (row, cc) holds global chunk (row, cc ^ ((row>>1)&3)).
    int srow = tid >> 2, scc = tid & 3;
    int sgc = scc ^ ((srow >> 1) & 3);

    // Reader: global chunk g = kk*2 + (lg>>1) lives at LDS chunk g^((row>>1)&3);
    // (row>>1)&3 == (l16>>1)&3 for every fragment row.
    int swz[2];
#pragma unroll
    for (int kk = 0; kk < 2; ++kk)
        swz[kk] = (((kk * 2 + (lg >> 1)) ^ ((l16 >> 1) & 3)) * 16) + (lg & 1) * 8;

    int arow[4], brow[2];
#pragma unroll
    for (int m = 0; m < 4; ++m) arow[m] = (wr * 64 + m * 16 + l16) * BK;
#pragma unroll
    for (int n = 0; n < 2; ++n) brow[n] = (wc * 32 + n * 16 + l16) * BK;

    f32x4 acc[4][2] = {};

    for (int k0 = 0; k0 < DIM; k0 += BK) {
        if (k0) __syncthreads();   // protect previous iter's LDS reads
        {
            const uint8_t* srcA = ynq + (size_t)(r0 + srow) * DIM + k0 + sgc * 16;
            __builtin_amdgcn_global_load_lds(
                (const __attribute__((address_space(1))) uint32_t*)srcA,
                (__attribute__((address_space(3))) uint32_t*)(As + wave * 1024), 16, 0, 0);
            const uint8_t* srcB = ynq + (size_t)(c0 + srow) * DIM + k0 + sgc * 16;
            __builtin_amdgcn_global_load_lds(
                (const __attribute__((address_space(1))) uint32_t*)srcB,
                (__attribute__((address_space(3))) uint32_t*)(Bs + wave * 1024), 16, 0, 0);
        }
        __syncthreads();   // drain; 3 co-resident blocks + 8 waves hide the stall

#pragma unroll
        for (int kk = 0; kk < 2; ++kk) {
            long a[4], b[2];
#pragma unroll
            for (int m = 0; m < 4; ++m) a[m] = *(const long*)(As + arow[m] + swz[kk]);
#pragma unroll
            for (int n = 0; n < 2; ++n) b[n] = *(const long*)(Bs + brow[n] + swz[kk]);
#pragma unroll
            for (int m = 0; m < 4; ++m)
#pragma unroll
                for (int n = 0; n < 2; ++n)
                    acc[m][n] = __builtin_amdgcn_mfma_f32_16x16x32_fp8_fp8(
                        a[m], b[n], acc[m][n], 0, 0, 0);
        }
    }

    // Epilogue. C/D layout (m89): col = lane&15, row = lg*4 + reg (within 16x16).
    bool diag = (by == bx);
    float colacc0 = 0.0f, colacc1 = 0.0f;
    float rp[16];
#pragma unroll
    for (int m = 0; m < 4; ++m) {
#pragma unroll
        for (int r2 = 0; r2 < 4; ++r2) {
            int grow = r0 + wr * 64 + m * 16 + lg * 4 + r2;
            float s0, s1;
            {
                float S = acc[m][0][r2];
                float e = __builtin_amdgcn_exp2f(S * EXP2C);
                if (diag) {
                    int gcol = c0 + wc * 32 + l16;
                    if (gcol == grow) e = 0.0f;
                    if (gcol == (grow ^ 1)) posterm[grow] = -S * TINV;
                }
                s0 = e; colacc0 += e;
            }
            {
                float S = acc[m][1][r2];
                float e = __builtin_amdgcn_exp2f(S * EXP2C);
                if (diag) {
                    int gcol = c0 + wc * 32 + 16 + l16;
                    if (gcol == grow) e = 0.0f;
                    if (gcol == (grow ^ 1)) posterm[grow] = -S * TINV;
                }
                s1 = e; colacc1 += e;
            }
            rp[m * 4 + r2] = s0 + s1;
        }
    }
    // Butterfly reduce-scatter over the 4 l16 bits: 15 shfl; lane l16 ends
    // holding the complete row-sum for rid = l16.
    int b0 = l16 & 1, b1 = (l16 >> 1) & 1, b2 = (l16 >> 2) & 1, b3 = (l16 >> 3) & 1;
    float t8[8];
#pragma unroll
    for (int i = 0; i < 8; ++i) {
        float send = b0 ? rp[2 * i] : rp[2 * i + 1];
        float keep = b0 ? rp[2 * i + 1] : rp[2 * i];
        t8[i] = keep + __shfl_xor(send, 1);
    }
    float t4[4];
#pragma unroll
    for (int i = 0; i < 4; ++i) {
        float send = b1 ? t8[2 * i] : t8[2 * i + 1];
        float keep = b1 ? t8[2 * i + 1] : t8[2 * i];
        t4[i] = keep + __shfl_xor(send, 2);
    }
    float t2[2];
#pragma unroll
    for (int i = 0; i < 2; ++i) {
        float send = b2 ? t4[2 * i] : t4[2 * i + 1];
        float keep = b2 ? t4[2 * i + 1] : t4[2 * i];
        t2[i] = keep + __shfl_xor(send, 4);
    }
    {
        float send = b3 ? t2[0] : t2[1];
        float keep = b3 ? t2[1] : t2[0];
        float rsum = keep + __shfl_xor(send, 8);
        int row_w = ((l16 >> 2) & 3) * 16 + lg * 4 + (l16 & 3);   // rid = l16
        rowpart[wc][wr * 64 + row_w] = rsum;                       // 1 write/lane
    }
    // col partials: xor 16/32 reduces over this wave's 64 rows (lg groups)
    colacc0 += __shfl_xor(colacc0, 16); colacc0 += __shfl_xor(colacc0, 32);
    colacc1 += __shfl_xor(colacc1, 16); colacc1 += __shfl_xor(colacc1, 32);
    if (!diag && lane < 16) {
        colpart[wr][wc * 32 + lane] = colacc0;
        colpart[wr][wc * 32 + 16 + lane] = colacc1;
    }
    __syncthreads();
    // Single-writer stores: threads 0..127 -> row sums, 128..255 -> col sums.
    if (tid < BM) {
        P[(size_t)bx * N + r0 + tid] =
            rowpart[0][tid] + rowpart[1][tid] + rowpart[2][tid] + rowpart[3][tid];
    } else if (tid < 2 * BM && !diag) {
        int lcol = tid - BM;
        P[(size_t)by * N + c0 + lcol] = colpart[0][lcol] + colpart[1][lcol];
    }
}

// Kernel 3: reduce + FUSED final via last-block ticket (no extra dispatch,
// no spinning, no counter reset needed): each of the NRED=128 single-wave
// blocks writes its partial, fence-releases, takes a ticket; the 128th
// arrival of THIS call (ticket & 127 == 127 -- any 128 consecutive tickets
// contain exactly one, so 0xAA poison / accumulation across replays is fine)
// fence-acquires and sums the 128 partials into out[0].
__global__ void nt_reduce_final(const float* __restrict__ P,
                                const float* __restrict__ posterm,
                                float* __restrict__ blockpart,
                                unsigned* __restrict__ cnt,
                                float* __restrict__ out, int N) {
    int lane = threadIdx.x;                     // 64 threads = 1 wave
    int row = blockIdx.x * 64 + lane;
    float s = 0.0f;
#pragma unroll
    for (int jj = 0; jj < NSLOT; ++jj) s += P[(size_t)jj * N + row];
    float v = posterm[row] + logf(s);
#pragma unroll
    for (int off = 1; off < 64; off <<= 1) v += __shfl_xor(v, off);
    unsigned ticket = 0;
    if (lane == 0) {
        blockpart[blockIdx.x] = v;
        __threadfence();                        // release: partial visible
        ticket = atomicAdd(cnt, 1u);
    }
    ticket = __shfl(ticket, 0);
    if ((ticket & (NRED - 1u)) == NRED - 1u) {  // last arrival of this call
        __threadfence();                        // acquire
        float w = __hip_atomic_load(&blockpart[lane], __ATOMIC_RELAXED,
                                    __HIP_MEMORY_SCOPE_AGENT) +
                  __hip_atomic_load(&blockpart[lane + 64], __ATOMIC_RELAXED,
                                    __HIP_MEMORY_SCOPE_AGENT);
#pragma unroll
        for (int off = 1; off < 64; off <<= 1) w += __shfl_xor(w, off);
        if (lane == 0) out[0] = w / (float)N;
    }
}

extern "C" void kernel_launch(void* const* d_in, const int* in_sizes, int n_in,
                              void* d_out, int out_size, void* d_ws, size_t ws_size,
                              hipStream_t stream) {
    const float* y = (const float*)d_in[0];
    int N = in_sizes[0] / DIM;                 // 8192
    int nt = N / BN;                           // 64
    uint8_t* ynq = (uint8_t*)d_ws;             // N*DIM fp8 = 2 MB
    float* posterm = (float*)((char*)d_ws + (size_t)N * DIM);       // 32 KB
    float* P = posterm + N;                    // nt*N f32 = 2 MB
    float* blockpart = P + (size_t)nt * N;     // NRED f32
    unsigned* cnt = (unsigned*)(blockpart + NRED);   // ticket counter (never reset)
    float* out = (float*)d_out;

    nt_normalize<<<N / 4, 256, 0, stream>>>(y, ynq, N);
    int T = nt * (nt + 1) / 2;                 // 2080 blocks, no dead work
    nt_gemm<<<T, 512, 0, stream>>>(ynq, P, posterm, N);
    nt_reduce_final<<<NRED, 64, 0, stream>>>(P, posterm, blockpart, cnt, out, N);
}

// Round 15
// 36.377 us; speedup vs baseline: 8.8655x; 1.0000x over previous
//
#include <hip/hip_runtime.h>
#include <hip/hip_bf16.h>
#include <cstdint>

typedef __attribute__((ext_vector_type(4))) float f32x4;

#define DIM 256
#define TINV 10.0f
// TINV * log2(e): exp(S/T) == exp2(S * EXP2C)
#define EXP2C 14.426950408889634f
#define BM 128
#define BN 128
#define BK 64
#define NSLOT 64   // N/BN, compile-time for full unroll in reduce
#define NRED 128   // reduce blocks (N/64); power of two for ticket mask

// Kernel 1: row-normalize y (f32) -> fp8 e4m3 (OCP, RNE via cvt_pk).
__global__ void nt_normalize(const float* __restrict__ y, uint8_t* __restrict__ ynq,
                             int N) {
    int tid = threadIdx.x;
    int wave = tid >> 6, lane = tid & 63;
    int row = blockIdx.x * 4 + wave;
    float4 v = ((const float4*)(y + (size_t)row * DIM))[lane];
    float ss = v.x * v.x + v.y * v.y + v.z * v.z + v.w * v.w;
#pragma unroll
    for (int off = 1; off < 64; off <<= 1) ss += __shfl_xor(ss, off);
    float inv = 1.0f / fmaxf(sqrtf(ss), 1e-8f);
    int w = __builtin_amdgcn_cvt_pk_fp8_f32(v.x * inv, v.y * inv, 0, false);
    w = __builtin_amdgcn_cvt_pk_fp8_f32(v.z * inv, v.w * inv, w, true);
    ((int*)(ynq + (size_t)row * DIM))[lane] = w;
}

// Kernel 2: fp8 sim-GEMM + exp + partials + pos capture.
// R14 structure (128x128 tile, 8 waves 2Mx4N, 2-way-free swizzle cc^((row>>1)&3),
// 4 blocks/CU) + R7's counted-vmcnt double-buffer schedule (T4): K=256 fully
// unrolled, 4 stages of 2 loads/thread, s_waitcnt vmcnt(2) covered by a full
// 16-MFMA compute phase; vmcnt(0) only before the last compute.
__launch_bounds__(512, 8)
__global__ void nt_gemm(const uint8_t* __restrict__ ynq, float* __restrict__ P,
                        float* __restrict__ posterm, int N) {
    const int nt = N / BN;                      // 64
    const int T = nt * (nt + 1) / 2;            // 2080
    // bijective XCD-chunked swizzle (m204)
    int orig = blockIdx.x;
    int q = T >> 3, r = T & 7;
    int xcd = orig & 7, loc = orig >> 3;
    int t = (xcd < r ? xcd * (q + 1) : r * (q + 1) + (xcd - r) * q) + loc;
    // triangular index -> (by, bx), by <= bx (count from bottom-right corner)
    int s = T - 1 - t;
    float f = sqrtf(8.0f * (float)s + 1.0f);
    int j = (int)((f - 1.0f) * 0.5f);
    while ((j + 1) * (j + 2) / 2 <= s) ++j;
    while (j * (j + 1) / 2 > s) --j;
    int k = s - j * (j + 1) / 2;
    int by = nt - 1 - j, bx = nt - 1 - k;

    __shared__ __align__(16) uint8_t As[2][BM * BK];   // 2 x 8 KB (fp8 K-tiles)
    __shared__ __align__(16) uint8_t Bs[2][BN * BK];   // 2 x 8 KB
    __shared__ float rowpart[4][BM];                   // 2 KB [wc][row-in-tile]
    __shared__ float colpart[2][BN];                   // 1 KB [wr][col-in-tile]

    int r0 = by * BM, c0 = bx * BN;
    int tid = threadIdx.x;
    int wave = tid >> 6, lane = tid & 63;
    int wr = wave >> 2, wc = wave & 3;               // 2 x 4 wave grid
    int l16 = lane & 15, lg = lane >> 4;

    // Staging: LDS chunk (row, cc) holds global chunk (row, cc ^ ((row>>1)&3)).
    int srow = tid >> 2, scc = tid & 3;
    int sgc = scc ^ ((srow >> 1) & 3);

    // Reader: global chunk g = kk*2 + (lg>>1) lives at LDS chunk g^((row>>1)&3);
    // (row>>1)&3 == (l16>>1)&3 for every fragment row. 2-way conflict = free.
    int swz[2];
#pragma unroll
    for (int kk = 0; kk < 2; ++kk)
        swz[kk] = (((kk * 2 + (lg >> 1)) ^ ((l16 >> 1) & 3)) * 16) + (lg & 1) * 8;

    int arow[4], brow[2];
#pragma unroll
    for (int m = 0; m < 4; ++m) arow[m] = (wr * 64 + m * 16 + l16) * BK;
#pragma unroll
    for (int n = 0; n < 2; ++n) brow[n] = (wc * 32 + n * 16 + l16) * BK;

    f32x4 acc[4][2] = {};

    // One K-stage into buffer b: 2 global_load_lds per thread (1 A + 1 B chunk).
#define STAGE(b, k0)                                                                \
    {                                                                               \
        const uint8_t* srcA = ynq + (size_t)(r0 + srow) * DIM + (k0) + sgc * 16;    \
        __builtin_amdgcn_global_load_lds(                                           \
            (const __attribute__((address_space(1))) uint32_t*)srcA,                \
            (__attribute__((address_space(3))) uint32_t*)(As[b] + wave * 1024),     \
            16, 0, 0);                                                              \
        const uint8_t* srcB = ynq + (size_t)(c0 + srow) * DIM + (k0) + sgc * 16;    \
        __builtin_amdgcn_global_load_lds(                                           \
            (const __attribute__((address_space(1))) uint32_t*)srcB,                \
            (__attribute__((address_space(3))) uint32_t*)(Bs[b] + wave * 1024),     \
            16, 0, 0);                                                              \
    }

#define COMPUTE(b)                                                                  \
    {                                                                               \
        __builtin_amdgcn_s_setprio(1);                                              \
        _Pragma("unroll")                                                           \
        for (int kk = 0; kk < 2; ++kk) {                                            \
            long a[4], b2[2];                                                       \
            _Pragma("unroll")                                                       \
            for (int m = 0; m < 4; ++m)                                             \
                a[m] = *(const long*)(As[b] + arow[m] + swz[kk]);                   \
            _Pragma("unroll")                                                       \
            for (int n = 0; n < 2; ++n)                                             \
                b2[n] = *(const long*)(Bs[b] + brow[n] + swz[kk]);                  \
            _Pragma("unroll")                                                       \
            for (int m = 0; m < 4; ++m)                                             \
                _Pragma("unroll")                                                   \
                for (int n = 0; n < 2; ++n)                                         \
                    acc[m][n] = __builtin_amdgcn_mfma_f32_16x16x32_fp8_fp8(         \
                        a[m], b2[n], acc[m][n], 0, 0, 0);                           \
        }                                                                           \
        __builtin_amdgcn_s_setprio(0);                                              \
    }

#define WAITV(n) asm volatile("s_waitcnt vmcnt(" #n ")" ::: "memory")
#define BAR() __builtin_amdgcn_s_barrier()

    STAGE(0, 0);              // vmcnt 2
    STAGE(1, 64);             // vmcnt 4
    WAITV(2); BAR();          // S0 landed (each wave waits its own, then joins)
    COMPUTE(0);               // C0 — S1 lands underneath
    BAR();                    // all waves done reading buf0
    STAGE(0, 128);            // S2
    WAITV(2); BAR();          // S1 landed (covered by C0)
    COMPUTE(1);               // C1 — S2 lands underneath
    BAR();                    // all waves done reading buf1
    STAGE(1, 192);            // S3
    WAITV(2); BAR();          // S2 landed (covered by C1)
    COMPUTE(0);               // C2 — S3 lands underneath
    WAITV(0); BAR();          // S3 landed (covered by C2)
    COMPUTE(1);               // C3

#undef STAGE
#undef COMPUTE
#undef WAITV
#undef BAR

    // Epilogue. C/D layout (m89): col = lane&15, row = lg*4 + reg (within 16x16).
    bool diag = (by == bx);
    float colacc0 = 0.0f, colacc1 = 0.0f;
    float rp[16];
#pragma unroll
    for (int m = 0; m < 4; ++m) {
#pragma unroll
        for (int r2 = 0; r2 < 4; ++r2) {
            int grow = r0 + wr * 64 + m * 16 + lg * 4 + r2;
            float s0, s1;
            {
                float S = acc[m][0][r2];
                float e = __builtin_amdgcn_exp2f(S * EXP2C);
                if (diag) {
                    int gcol = c0 + wc * 32 + l16;
                    if (gcol == grow) e = 0.0f;
                    if (gcol == (grow ^ 1)) posterm[grow] = -S * TINV;
                }
                s0 = e; colacc0 += e;
            }
            {
                float S = acc[m][1][r2];
                float e = __builtin_amdgcn_exp2f(S * EXP2C);
                if (diag) {
                    int gcol = c0 + wc * 32 + 16 + l16;
                    if (gcol == grow) e = 0.0f;
                    if (gcol == (grow ^ 1)) posterm[grow] = -S * TINV;
                }
                s1 = e; colacc1 += e;
            }
            rp[m * 4 + r2] = s0 + s1;
        }
    }
    // Butterfly reduce-scatter over the 4 l16 bits: 15 shfl; lane l16 ends
    // holding the complete row-sum for rid = l16.
    int b0 = l16 & 1, b1 = (l16 >> 1) & 1, b2 = (l16 >> 2) & 1, b3 = (l16 >> 3) & 1;
    float t8[8];
#pragma unroll
    for (int i = 0; i < 8; ++i) {
        float send = b0 ? rp[2 * i] : rp[2 * i + 1];
        float keep = b0 ? rp[2 * i + 1] : rp[2 * i];
        t8[i] = keep + __shfl_xor(send, 1);
    }
    float t4[4];
#pragma unroll
    for (int i = 0; i < 4; ++i) {
        float send = b1 ? t8[2 * i] : t8[2 * i + 1];
        float keep = b1 ? t8[2 * i + 1] : t8[2 * i];
        t4[i] = keep + __shfl_xor(send, 2);
    }
    float t2[2];
#pragma unroll
    for (int i = 0; i < 2; ++i) {
        float send = b2 ? t4[2 * i] : t4[2 * i + 1];
        float keep = b2 ? t4[2 * i + 1] : t4[2 * i];
        t2[i] = keep + __shfl_xor(send, 4);
    }
    {
        float send = b3 ? t2[0] : t2[1];
        float keep = b3 ? t2[1] : t2[0];
        float rsum = keep + __shfl_xor(send, 8);
        int row_w = ((l16 >> 2) & 3) * 16 + lg * 4 + (l16 & 3);   // rid = l16
        rowpart[wc][wr * 64 + row_w] = rsum;                       // 1 write/lane
    }
    // col partials: xor 16/32 reduces over this wave's 64 rows (lg groups)
    colacc0 += __shfl_xor(colacc0, 16); colacc0 += __shfl_xor(colacc0, 32);
    colacc1 += __shfl_xor(colacc1, 16); colacc1 += __shfl_xor(colacc1, 32);
    if (!diag && lane < 16) {
        colpart[wr][wc * 32 + lane] = colacc0;
        colpart[wr][wc * 32 + 16 + lane] = colacc1;
    }
    __syncthreads();
    // Single-writer stores: threads 0..127 -> row sums, 128..255 -> col sums.
    if (tid < BM) {
        P[(size_t)bx * N + r0 + tid] =
            rowpart[0][tid] + rowpart[1][tid] + rowpart[2][tid] + rowpart[3][tid];
    } else if (tid < 2 * BM && !diag) {
        int lcol = tid - BM;
        P[(size_t)by * N + c0 + lcol] = colpart[0][lcol] + colpart[1][lcol];
    }
}

// Kernel 3: reduce + FUSED final via last-block ticket (no extra dispatch,
// no spinning; ticket & 127 == 127 identifies this call's last arrival --
// poison/accumulation across replays is harmless).
__global__ void nt_reduce_final(const float* __restrict__ P,
                                const float* __restrict__ posterm,
                                float* __restrict__ blockpart,
                                unsigned* __restrict__ cnt,
                                float* __restrict__ out, int N) {
    int lane = threadIdx.x;                     // 64 threads = 1 wave
    int row = blockIdx.x * 64 + lane;
    float s = 0.0f;
#pragma unroll
    for (int jj = 0; jj < NSLOT; ++jj) s += P[(size_t)jj * N + row];
    float v = posterm[row] + logf(s);
#pragma unroll
    for (int off = 1; off < 64; off <<= 1) v += __shfl_xor(v, off);
    unsigned ticket = 0;
    if (lane == 0) {
        blockpart[blockIdx.x] = v;
        __threadfence();                        // release: partial visible
        ticket = atomicAdd(cnt, 1u);
    }
    ticket = __shfl(ticket, 0);
    if ((ticket & (NRED - 1u)) == NRED - 1u) {  // last arrival of this call
        __threadfence();                        // acquire
        float w = __hip_atomic_load(&blockpart[lane], __ATOMIC_RELAXED,
                                    __HIP_MEMORY_SCOPE_AGENT) +
                  __hip_atomic_load(&blockpart[lane + 64], __ATOMIC_RELAXED,
                                    __HIP_MEMORY_SCOPE_AGENT);
#pragma unroll
        for (int off = 1; off < 64; off <<= 1) w += __shfl_xor(w, off);
        if (lane == 0) out[0] = w / (float)N;
    }
}

extern "C" void kernel_launch(void* const* d_in, const int* in_sizes, int n_in,
                              void* d_out, int out_size, void* d_ws, size_t ws_size,
                              hipStream_t stream) {
    const float* y = (const float*)d_in[0];
    int N = in_sizes[0] / DIM;                 // 8192
    int nt = N / BN;                           // 64
    uint8_t* ynq = (uint8_t*)d_ws;             // N*DIM fp8 = 2 MB
    float* posterm = (float*)((char*)d_ws + (size_t)N * DIM);       // 32 KB
    float* P = posterm + N;                    // nt*N f32 = 2 MB
    float* blockpart = P + (size_t)nt * N;     // NRED f32
    unsigned* cnt = (unsigned*)(blockpart + NRED);   // ticket counter (never reset)
    float* out = (float*)d_out;

    nt_normalize<<<N / 4, 256, 0, stream>>>(y, ynq, N);
    int T = nt * (nt + 1) / 2;                 // 2080 blocks, no dead work
    nt_gemm<<<T, 512, 0, stream>>>(ynq, P, posterm, N);
    nt_reduce_final<<<NRED, 64, 0, stream>>>(P, posterm, blockpart, cnt, out, N);
}

// Round 16
// 34.299 us; speedup vs baseline: 9.4027x; 1.0606x over previous
//
#include <hip/hip_runtime.h>
#include <hip/hip_bf16.h>
#include <cstdint>

typedef __attribute__((ext_vector_type(4))) float f32x4;
typedef __attribute__((ext_vector_type(2))) long long2_t;

#define DIM 256
#define TINV 10.0f
// TINV * log2(e): exp(S/T) == exp2(S * EXP2C)
#define EXP2C 14.426950408889634f
#define BM 128
#define BN 128
#define BK 64
#define NSLOT 64   // N/BN, compile-time for full unroll in reduce
#define NRED 32    // reduce blocks (N/(64*4)); power of two for ticket mask

// Kernel 1: row-normalize y (f32) -> fp8 e4m3, written PAIR-INTERLEAVED:
// within each 64B row-block, original 8B-unit u lands at byte 16*(u&3)+8*(u>>2),
// so units {g, g+4} (= one lane's kk0/kk1 MFMA pieces) form one contiguous
// 16B chunk. ynq is private scratch; gemm reads match this format.
__global__ void nt_normalize(const float* __restrict__ y, uint8_t* __restrict__ ynq,
                             int N) {
    int tid = threadIdx.x;
    int wave = tid >> 6, lane = tid & 63;
    int row = blockIdx.x * 4 + wave;
    float4 v = ((const float4*)(y + (size_t)row * DIM))[lane];
    float ss = v.x * v.x + v.y * v.y + v.z * v.z + v.w * v.w;
#pragma unroll
    for (int off = 1; off < 64; off <<= 1) ss += __shfl_xor(ss, off);
    float inv = 1.0f / fmaxf(sqrtf(ss), 1e-8f);
    int w = __builtin_amdgcn_cvt_pk_fp8_f32(v.x * inv, v.y * inv, 0, false);
    w = __builtin_amdgcn_cvt_pk_fp8_f32(v.z * inv, v.w * inv, w, true);
    // lane covers original fp8 bytes [4*lane, 4*lane+4): unit u_row = lane>>1,
    // half h = lane&1. Permuted: block = u_row>>3, u = u_row&7.
    int u_row = lane >> 1;
    int addr = (u_row >> 3) * 64 + (((u_row & 7) & 3) << 4) + (((u_row & 7) >> 2) << 3)
               + ((lane & 1) << 2);
    *(int*)(ynq + (size_t)row * DIM + addr) = w;
}

// Kernel 2: fp8 sim-GEMM + exp + partials + pos capture.
// R14 structure (128x128 tile, 8 waves 2Mx4N, BK=64, 4 blocks/CU, triangular
// grid, single-writer P). NEW: pair-interleaved ynq => A-frags load as ONE
// ds_read_b128 (lo 8B = kk0, hi 8B = kk1) at slot lg^(l16&3) — audit:
// bank-group 16(r&1)+4*slot covers 8 x 16B spans evenly = CONFLICT-FREE.
// B-frags: ds_read_b64 at slot*16 + kk*8. LDS instrs 12 -> 8 per wave-tile.
__launch_bounds__(512, 8)
__global__ void nt_gemm(const uint8_t* __restrict__ ynq, float* __restrict__ P,
                        float* __restrict__ posterm, int N) {
    const int nt = N / BN;                      // 64
    const int T = nt * (nt + 1) / 2;            // 2080
    // bijective XCD-chunked swizzle (m204)
    int orig = blockIdx.x;
    int q = T >> 3, r = T & 7;
    int xcd = orig & 7, loc = orig >> 3;
    int t = (xcd < r ? xcd * (q + 1) : r * (q + 1) + (xcd - r) * q) + loc;
    // triangular index -> (by, bx), by <= bx (count from bottom-right corner)
    int s = T - 1 - t;
    float f = sqrtf(8.0f * (float)s + 1.0f);
    int j = (int)((f - 1.0f) * 0.5f);
    while ((j + 1) * (j + 2) / 2 <= s) ++j;
    while (j * (j + 1) / 2 > s) --j;
    int k = s - j * (j + 1) / 2;
    int by = nt - 1 - j, bx = nt - 1 - k;

    __shared__ __align__(16) uint8_t As[BM * BK];    // 8 KB (fp8 K-tile)
    __shared__ __align__(16) uint8_t Bs[BN * BK];    // 8 KB
    __shared__ float rowpart[4][BM];                 // 2 KB [wc][row-in-tile]
    __shared__ float colpart[2][BN];                 // 1 KB [wr][col-in-tile]

    int r0 = by * BM, c0 = bx * BN;
    int tid = threadIdx.x;
    int wave = tid >> 6, lane = tid & 63;
    int wr = wave >> 2, wc = wave & 3;               // 2 x 4 wave grid
    int l16 = lane & 15, lg = lane >> 4;

    // Staging: LDS 16B slot (row, cc) holds permuted-global chunk cc ^ (row&3).
    int srow = tid >> 2, scc = tid & 3;
    int sgc = scc ^ (srow & 3);

    // Reader: pair lg (lane's kk0+kk1 data) stored at slot lg ^ (row&3);
    // row&3 == l16&3 for every fragment row.
    int slot16 = (lg ^ (l16 & 3)) * 16;              // per-lane constant byte offset

    int arow[4], brow[2];
#pragma unroll
    for (int m = 0; m < 4; ++m) arow[m] = (wr * 64 + m * 16 + l16) * BK;
#pragma unroll
    for (int n = 0; n < 2; ++n) brow[n] = (wc * 32 + n * 16 + l16) * BK;

    f32x4 acc[4][2] = {};

    for (int k0 = 0; k0 < DIM; k0 += BK) {
        if (k0) __syncthreads();   // protect previous iter's LDS reads
        {
            const uint8_t* srcA = ynq + (size_t)(r0 + srow) * DIM + k0 + sgc * 16;
            __builtin_amdgcn_global_load_lds(
                (const __attribute__((address_space(1))) uint32_t*)srcA,
                (__attribute__((address_space(3))) uint32_t*)(As + wave * 1024), 16, 0, 0);
            const uint8_t* srcB = ynq + (size_t)(c0 + srow) * DIM + k0 + sgc * 16;
            __builtin_amdgcn_global_load_lds(
                (const __attribute__((address_space(1))) uint32_t*)srcB,
                (__attribute__((address_space(3))) uint32_t*)(Bs + wave * 1024), 16, 0, 0);
        }
        __syncthreads();   // drain; 3 co-resident blocks + 8 waves hide the stall

        // A: 4 x ds_read_b128 (conflict-free), both kk pieces per read.
        long2_t a2[4];
#pragma unroll
        for (int m = 0; m < 4; ++m)
            a2[m] = *(const long2_t*)(As + arow[m] + slot16);
#pragma unroll
        for (int kk = 0; kk < 2; ++kk) {
            long b2[2];
#pragma unroll
            for (int n = 0; n < 2; ++n)
                b2[n] = *(const long*)(Bs + brow[n] + slot16 + kk * 8);
#pragma unroll
            for (int m = 0; m < 4; ++m) {
                long am = kk ? a2[m].y : a2[m].x;
#pragma unroll
                for (int n = 0; n < 2; ++n)
                    acc[m][n] = __builtin_amdgcn_mfma_f32_16x16x32_fp8_fp8(
                        am, b2[n], acc[m][n], 0, 0, 0);
            }
        }
    }

    // Epilogue. C/D layout (m89): col = lane&15, row = lg*4 + reg (within 16x16).
    bool diag = (by == bx);
    float colacc0 = 0.0f, colacc1 = 0.0f;
    float rp[16];
#pragma unroll
    for (int m = 0; m < 4; ++m) {
#pragma unroll
        for (int r2 = 0; r2 < 4; ++r2) {
            int grow = r0 + wr * 64 + m * 16 + lg * 4 + r2;
            float s0, s1;
            {
                float S = acc[m][0][r2];
                float e = __builtin_amdgcn_exp2f(S * EXP2C);
                if (diag) {
                    int gcol = c0 + wc * 32 + l16;
                    if (gcol == grow) e = 0.0f;
                    if (gcol == (grow ^ 1)) posterm[grow] = -S * TINV;
                }
                s0 = e; colacc0 += e;
            }
            {
                float S = acc[m][1][r2];
                float e = __builtin_amdgcn_exp2f(S * EXP2C);
                if (diag) {
                    int gcol = c0 + wc * 32 + 16 + l16;
                    if (gcol == grow) e = 0.0f;
                    if (gcol == (grow ^ 1)) posterm[grow] = -S * TINV;
                }
                s1 = e; colacc1 += e;
            }
            rp[m * 4 + r2] = s0 + s1;
        }
    }
    // Butterfly reduce-scatter over the 4 l16 bits: 15 shfl; lane l16 ends
    // holding the complete row-sum for rid = l16.
    int b0 = l16 & 1, b1 = (l16 >> 1) & 1, b2_ = (l16 >> 2) & 1, b3 = (l16 >> 3) & 1;
    float t8[8];
#pragma unroll
    for (int i = 0; i < 8; ++i) {
        float send = b0 ? rp[2 * i] : rp[2 * i + 1];
        float keep = b0 ? rp[2 * i + 1] : rp[2 * i];
        t8[i] = keep + __shfl_xor(send, 1);
    }
    float t4[4];
#pragma unroll
    for (int i = 0; i < 4; ++i) {
        float send = b1 ? t8[2 * i] : t8[2 * i + 1];
        float keep = b1 ? t8[2 * i + 1] : t8[2 * i];
        t4[i] = keep + __shfl_xor(send, 2);
    }
    float t2[2];
#pragma unroll
    for (int i = 0; i < 2; ++i) {
        float send = b2_ ? t4[2 * i] : t4[2 * i + 1];
        float keep = b2_ ? t4[2 * i + 1] : t4[2 * i];
        t2[i] = keep + __shfl_xor(send, 4);
    }
    {
        float send = b3 ? t2[0] : t2[1];
        float keep = b3 ? t2[1] : t2[0];
        float rsum = keep + __shfl_xor(send, 8);
        int row_w = ((l16 >> 2) & 3) * 16 + lg * 4 + (l16 & 3);   // rid = l16
        rowpart[wc][wr * 64 + row_w] = rsum;                       // 1 write/lane
    }
    // col partials: xor 16/32 reduces over this wave's 64 rows (lg groups)
    colacc0 += __shfl_xor(colacc0, 16); colacc0 += __shfl_xor(colacc0, 32);
    colacc1 += __shfl_xor(colacc1, 16); colacc1 += __shfl_xor(colacc1, 32);
    if (!diag && lane < 16) {
        colpart[wr][wc * 32 + lane] = colacc0;
        colpart[wr][wc * 32 + 16 + lane] = colacc1;
    }
    __syncthreads();
    // Single-writer stores: threads 0..127 -> row sums, 128..255 -> col sums.
    if (tid < BM) {
        P[(size_t)bx * N + r0 + tid] =
            rowpart[0][tid] + rowpart[1][tid] + rowpart[2][tid] + rowpart[3][tid];
    } else if (tid < 2 * BM && !diag) {
        int lcol = tid - BM;
        P[(size_t)by * N + c0 + lcol] = colpart[0][lcol] + colpart[1][lcol];
    }
}

// Kernel 3: reduce + fused final via last-block ticket. VECTORIZED: 32 blocks
// x 1 wave; each lane owns 4 consecutive rows, reading float4 per P slot
// (wave reads 1 KB contiguous per slot) — 1/4 the loads of the scalar form.
__global__ void nt_reduce_final(const float* __restrict__ P,
                                const float* __restrict__ posterm,
                                float* __restrict__ blockpart,
                                unsigned* __restrict__ cnt,
                                float* __restrict__ out, int N) {
    int lane = threadIdx.x;                     // 64 threads = 1 wave
    int gid = blockIdx.x * 64 + lane;           // float4 index over rows
    f32x4 ps = {0.0f, 0.0f, 0.0f, 0.0f};
#pragma unroll
    for (int jj = 0; jj < NSLOT; ++jj)
        ps += ((const f32x4*)(P + (size_t)jj * N))[gid];
    f32x4 pt = ((const f32x4*)posterm)[gid];
    float v = (pt[0] + logf(ps[0])) + (pt[1] + logf(ps[1])) +
              (pt[2] + logf(ps[2])) + (pt[3] + logf(ps[3]));
#pragma unroll
    for (int off = 1; off < 64; off <<= 1) v += __shfl_xor(v, off);
    unsigned ticket = 0;
    if (lane == 0) {
        blockpart[blockIdx.x] = v;
        __threadfence();                        // release: partial visible
        ticket = atomicAdd(cnt, 1u);
    }
    ticket = __shfl(ticket, 0);
    if ((ticket & (NRED - 1u)) == NRED - 1u) {  // last arrival of this call
        __threadfence();                        // acquire
        float w = (lane < NRED)
                      ? __hip_atomic_load(&blockpart[lane], __ATOMIC_RELAXED,
                                          __HIP_MEMORY_SCOPE_AGENT)
                      : 0.0f;
#pragma unroll
        for (int off = 1; off < 64; off <<= 1) w += __shfl_xor(w, off);
        if (lane == 0) out[0] = w / (float)N;
    }
}

extern "C" void kernel_launch(void* const* d_in, const int* in_sizes, int n_in,
                              void* d_out, int out_size, void* d_ws, size_t ws_size,
                              hipStream_t stream) {
    const float* y = (const float*)d_in[0];
    int N = in_sizes[0] / DIM;                 // 8192
    int nt = N / BN;                           // 64
    uint8_t* ynq = (uint8_t*)d_ws;             // N*DIM fp8 = 2 MB (pair-interleaved)
    float* posterm = (float*)((char*)d_ws + (size_t)N * DIM);       // 32 KB
    float* P = posterm + N;                    // nt*N f32 = 2 MB
    float* blockpart = P + (size_t)nt * N;     // NRED f32
    unsigned* cnt = (unsigned*)(blockpart + NRED);   // ticket counter (never reset)
    float* out = (float*)d_out;

    nt_normalize<<<N / 4, 256, 0, stream>>>(y, ynq, N);
    int T = nt * (nt + 1) / 2;                 // 2080 blocks, no dead work
    nt_gemm<<<T, 512, 0, stream>>>(ynq, P, posterm, N);
    nt_reduce_final<<<NRED, 64, 0, stream>>>(P, posterm, blockpart, cnt, out, N);
}